// Round 26
// baseline (4723.437 us; speedup 1.0000x reference)
//
#include <hip/hip_runtime.h>
#include <cstdint>

#define NB 8
#define CIN 512
#define CMID 512
#define HW 4096            // 64*64
#define NA 9
#define NANCH 36864        // HW*NA
#define PRE_NMS 6000
#define POST_NMS 300
#define NMS_WORDS 94       // ceil(6000/64)

typedef unsigned long long u64;
typedef unsigned int u32;

__device__ __forceinline__ u32 fkey(float s) {
  u32 u = __float_as_uint(s);
  return (u & 0x80000000u) ? ~u : (u | 0x80000000u);
}

// W2f[((ci*9)+k)*512 + co] = conv_w[(co*512+ci)*9 + k]  (f32, coalescing transpose)
__global__ __launch_bounds__(256) void transpose_w3(const float* __restrict__ W, float* __restrict__ W2f) {
  int id = blockIdx.x * 256 + threadIdx.x;
  if (id >= CIN * CMID * 9) return;
  int co = id & 511;
  int rem = id >> 9;
  int k = rem % 9;
  int ci = rem / 9;
  W2f[id] = W[((size_t)co * CIN + ci) * 9 + k];
}

// ---- LDS-tiled conv3x3: f32 FMAs, f64 master flushed every 2 c0-steps ----
// r24 base (grid: co fastest) + f32 rolling row-cache (rows read once per ci;
// same values, same FMA order -> value-stream identical to r24) + 72-term f32
// chunks (error ~6e-8 mid, ~20x below the round-8 pick-flip level).
__global__ __launch_bounds__(256, 4) void conv3x3_mix(const float* __restrict__ X, const float* __restrict__ W2f,
                                                      const float* __restrict__ bias, float* __restrict__ midC,
                                                      int co_base, int chM) {
  const int co0 = co_base + blockIdx.x * 64;
  const int y0 = blockIdx.y * 2;
  const int b = blockIdx.z;
  __shared__ float sXf[4 * 4 * 66];   // flat [ci][rr][xx]  (4.2 KB)
  __shared__ float sWf[4 * 9 * 64];   // flat [ci][k][co]   (9.2 KB)
  const int t = threadIdx.x;
  const int tc = t >> 4, tx = t & 15;

  // ---- precomputed staging descriptors (loop-invariant) ----
  int xoff[5];   // -1: no slot; -2: zero-fill (OOB halo); >=0: X offset (const part)
#pragma unroll
  for (int s = 0; s < 5; s++) {
    const int i = t + 256 * s;
    int off = -1;
    if (i < 4 * 4 * 66) {
      const int xx = i % 66;
      const int rr = (i / 66) & 3;
      const int ci = i / 264;
      const int gy = y0 - 1 + rr, gx = xx - 1;
      off = ((unsigned)gy < 64u && (unsigned)gx < 64u) ? (ci * HW + gy * 64 + gx) : -2;
    }
    xoff[s] = off;
  }
  int woff[9];
#pragma unroll
  for (int s = 0; s < 9; s++) {
    const int i = t + 256 * s;
    const int co = i & 63;
    const int r2 = i >> 6;
    woff[s] = r2 * CMID + co0 + co;
  }

  double acc[4][2][4];
#pragma unroll
  for (int j = 0; j < 4; j++)
#pragma unroll
    for (int r = 0; r < 2; r++)
#pragma unroll
      for (int q = 0; q < 4; q++) acc[j][r][q] = 0.0;

  float sacc[4][2][4];   // f32 chunk accumulator (72 terms = 2 c0-steps)
#pragma unroll
  for (int j = 0; j < 4; j++)
#pragma unroll
    for (int r = 0; r < 2; r++)
#pragma unroll
      for (int q = 0; q < 4; q++) sacc[j][r][q] = 0.f;

#define FMABLOCK(KY, LO, HI)                                                          \
  {                                                                                   \
    _Pragma("unroll")                                                                 \
    for (int kx = 0; kx < 3; kx++) {                                                  \
      const float* wp = &sWf[ci * 576 + ((KY) * 3 + kx) * 64 + tc * 4];               \
      const float w0 = wp[0], w1 = wp[1], w2 = wp[2], w3 = wp[3];                     \
      _Pragma("unroll")                                                               \
      for (int q = 0; q < 4; q++) {                                                   \
        const float a0 = LO[q + kx];                                                  \
        const float a1 = HI[q + kx];                                                  \
        sacc[0][0][q] = fmaf(w0, a0, sacc[0][0][q]);                                  \
        sacc[1][0][q] = fmaf(w1, a0, sacc[1][0][q]);                                  \
        sacc[2][0][q] = fmaf(w2, a0, sacc[2][0][q]);                                  \
        sacc[3][0][q] = fmaf(w3, a0, sacc[3][0][q]);                                  \
        sacc[0][1][q] = fmaf(w0, a1, sacc[0][1][q]);                                  \
        sacc[1][1][q] = fmaf(w1, a1, sacc[1][1][q]);                                  \
        sacc[2][1][q] = fmaf(w2, a1, sacc[2][1][q]);                                  \
        sacc[3][1][q] = fmaf(w3, a1, sacc[3][1][q]);                                  \
      }                                                                               \
    }                                                                                 \
  }

  const float* Xb = X + (size_t)b * CIN * HW;
  for (int c0 = 0; c0 < CIN; c0 += 4) {
    const float* Xc = Xb + (size_t)c0 * HW;
    const float* Wc = W2f + (size_t)c0 * 9 * CMID;
#pragma unroll
    for (int s = 0; s < 5; s++) {
      const int off = xoff[s];
      if (off != -1) {
        float v = 0.f;
        if (off >= 0) v = Xc[off];
        sXf[t + 256 * s] = v;
      }
    }
#pragma unroll
    for (int s = 0; s < 9; s++) {
      sWf[t + 256 * s] = Wc[woff[s]];
    }
    __syncthreads();

#pragma unroll
    for (int ci = 0; ci < 4; ci++) {
      float xA[6], xB[6];
      const int rb = ci * 264 + tx * 4;
#pragma unroll
      for (int q = 0; q < 6; q++) xA[q] = sXf[rb + 0 * 66 + q];   // row 0
#pragma unroll
      for (int q = 0; q < 6; q++) xB[q] = sXf[rb + 1 * 66 + q];   // row 1
      FMABLOCK(0, xA, xB)                                          // rows (0,1)
#pragma unroll
      for (int q = 0; q < 6; q++) xA[q] = sXf[rb + 2 * 66 + q];   // row 2
      FMABLOCK(1, xB, xA)                                          // rows (1,2)
#pragma unroll
      for (int q = 0; q < 6; q++) xB[q] = sXf[rb + 3 * 66 + q];   // row 3
      FMABLOCK(2, xA, xB)                                          // rows (2,3)
    }
    // flush f32 chunk into f64 master every 2 c0-steps (and at the end)
    if ((c0 & 4) != 0) {
#pragma unroll
      for (int j = 0; j < 4; j++)
#pragma unroll
        for (int r = 0; r < 2; r++)
#pragma unroll
          for (int q = 0; q < 4; q++) {
            acc[j][r][q] += (double)sacc[j][r][q];
            sacc[j][r][q] = 0.f;
          }
    }
    __syncthreads();
  }
#undef FMABLOCK
#pragma unroll
  for (int j = 0; j < 4; j++) {
    const int co = co0 + tc * 4 + j;
    const double bv = (double)bias[co];
#pragma unroll
    for (int r = 0; r < 2; r++) {
      float4 o4;
      o4.x = (float)fmax(acc[j][r][0] + bv, 0.0);
      o4.y = (float)fmax(acc[j][r][1] + bv, 0.0);
      o4.z = (float)fmax(acc[j][r][2] + bv, 0.0);
      o4.w = (float)fmax(acc[j][r][3] + bv, 0.0);
      *(float4*)&midC[((size_t)b * chM + (co - co_base)) * HW + (y0 + r) * 64 + tx * 4] = o4;
    }
  }
}

// ---- merged 1x1 (cls 18 + bbox 36), FP64 accumulate over chM channels ----
__global__ __launch_bounds__(256) void conv1x1_f64(const float* __restrict__ midC, const float* __restrict__ clsW,
                                                   const float* __restrict__ bboxW, double* __restrict__ acc54,
                                                   int co_base, int chM, int first) {
  const int b = blockIdx.y;
  const int pix = blockIdx.x * 256 + threadIdx.x;
  const float* mb = midC + (size_t)b * chM * HW + pix;
  double a[54];
#pragma unroll
  for (int o = 0; o < 54; o++) a[o] = 0.0;
  for (int c = 0; c < chM; c++) {
    const double xv = (double)mb[(size_t)c * HW];
    const int ci = co_base + c;
#pragma unroll
    for (int o = 0; o < 18; o++) a[o] = fma(xv, (double)clsW[(size_t)o * CIN + ci], a[o]);
#pragma unroll
    for (int o = 0; o < 36; o++) a[18 + o] = fma(xv, (double)bboxW[(size_t)o * CIN + ci], a[18 + o]);
  }
  double* ap = acc54 + ((size_t)b * HW + pix) * 54;
  if (first) {
#pragma unroll
    for (int o = 0; o < 54; o++) ap[o] = a[o];
  } else {
#pragma unroll
    for (int o = 0; o < 54; o++) ap[o] += a[o];
  }
}

// ---- softmax + anchor decode + key build, FP64 math, f32 at np-visible points ----
__global__ __launch_bounds__(256) void decode_f64(const double* __restrict__ acc54,
                                                  const float* __restrict__ clsB, const float* __restrict__ bboxB,
                                                  const float* __restrict__ im_info,
                                                  float* __restrict__ probOut, float* __restrict__ bboxOut,
                                                  float* __restrict__ boxes, u64* __restrict__ keys) {
  const int b = blockIdx.y;
  const int pix = blockIdx.x * 256 + threadIdx.x;
  const double* ap = acc54 + ((size_t)b * HW + pix) * 54;
  double c[18];
#pragma unroll
  for (int o = 0; o < 18; o++) c[o] = ap[o] + (double)clsB[o];

  const int h = pix >> 6, w = pix & 63;
  float* pb = probOut + (size_t)b * 18 * HW + pix;
  float* bb = bboxOut + (size_t)b * 36 * HW + pix;
#pragma unroll
  for (int o = 0; o < 36; o++) bb[(size_t)o * HW] = (float)(ap[18 + o] + (double)bboxB[o]);

  const float imWm1 = im_info[b * 3 + 1] - 1.0f;
  const float imHm1 = im_info[b * 3 + 0] - 1.0f;
  const float msf = 16.0f * im_info[b * 3 + 2];
  float4* bxout = (float4*)(boxes + ((size_t)b * NANCH + (size_t)pix * NA) * 4);
  u64* kout = keys + (size_t)b * NANCH + (size_t)pix * NA;
  const float ratios[3] = {0.5f, 1.0f, 2.0f};
  const float scales[3] = {8.0f, 16.0f, 32.0f};
#pragma unroll
  for (int a = 0; a < NA; a++) {
    const double c0v = c[a], c1v = c[9 + a];
    const double m = fmax(c0v, c1v);
    const double e0 = exp(c0v - m), e1 = exp(c1v - m);
    const double s = e0 + e1;
    pb[(size_t)a * HW] = (float)(e0 / s);
    const double p1 = e1 / s;
    pb[(size_t)(9 + a) * HW] = (float)p1;

    const double dx = ap[18 + 4 * a + 0] + (double)bboxB[4 * a + 0];
    const double dy = ap[18 + 4 * a + 1] + (double)bboxB[4 * a + 1];
    const double dw = ap[18 + 4 * a + 2] + (double)bboxB[4 * a + 2];
    const double dh = ap[18 + 4 * a + 3] + (double)bboxB[4 * a + 3];

    const float sq = sqrtf(ratios[a / 3]);
    const float wa = (16.0f / sq) * scales[a % 3];
    const float ha = (16.0f * sq) * scales[a % 3];
    const float ax1 = (7.5f - 0.5f * (wa - 1.0f)) + (float)(w * 16);
    const float ay1 = (7.5f - 0.5f * (ha - 1.0f)) + (float)(h * 16);
    const float ax2 = (7.5f + 0.5f * (wa - 1.0f)) + (float)(w * 16);
    const float ay2 = (7.5f + 0.5f * (ha - 1.0f)) + (float)(h * 16);
    const float awf = ax2 - ax1 + 1.0f;
    const float ahf = ay2 - ay1 + 1.0f;
    const float cxf = ax1 + 0.5f * awf;
    const float cyf = ay1 + 0.5f * ahf;

    const double pcx = dx * (double)awf + (double)cxf;
    const double pcy = dy * (double)ahf + (double)cyf;
    const double pw = exp(dw) * (double)awf;
    const double ph = exp(dh) * (double)ahf;
    double x1 = pcx - 0.5 * pw;
    double y1 = pcy - 0.5 * ph;
    double x2 = pcx + 0.5 * pw;
    double y2 = pcy + 0.5 * ph;
    x1 = fmin(fmax(x1, 0.0), (double)imWm1);
    y1 = fmin(fmax(y1, 0.0), (double)imHm1);
    x2 = fmin(fmax(x2, 0.0), (double)imWm1);
    y2 = fmin(fmax(y2, 0.0), (double)imHm1);
    const float x1f = (float)x1, y1f = (float)y1, x2f = (float)x2, y2f = (float)y2;
    const bool ok = (x2f - x1f + 1.0f >= msf) && (y2f - y1f + 1.0f >= msf);
    const float sc = ok ? (float)p1 : -1000000000.0f;
    float4 bo;
    bo.x = x1f; bo.y = y1f; bo.z = x2f; bo.w = y2f;
    bxout[a] = bo;
    const u32 n = (u32)(pix * NA + a);
    kout[a] = ((u64)fkey(sc) << 32) | (u64)(0xFFFFFFFFu - n);
  }
}

// ---- exact top-6000: radix select on unique keys + bitonic sort + gather ----
__global__ __launch_bounds__(1024) void topk_sort(const u64* __restrict__ keys, const float* __restrict__ boxes,
                                                  float* __restrict__ sortedBoxes) {
  const int b = blockIdx.x;
  const int t = threadIdx.x;
  __shared__ u64 skeys[8192];   // 64 KiB static
  __shared__ u32 hist[256];
  __shared__ u64 s_prefix;
  __shared__ u32 s_T, s_cnt;
  const u64* kb = keys + (size_t)b * NANCH;
  if (t == 0) { s_prefix = 0ull; s_T = PRE_NMS; s_cnt = 0u; }
  __syncthreads();
  for (int pass = 0; pass < 8; pass++) {
    const int shift = 56 - 8 * pass;
    if (t < 256) hist[t] = 0u;
    __syncthreads();
    const u64 pfx = s_prefix;
    for (int i = t; i < NANCH; i += 1024) {
      const u64 k = kb[i];
      if (pass == 0 || (k >> (shift + 8)) == pfx)
        atomicAdd(&hist[(u32)((k >> shift) & 255ull)], 1u);
    }
    __syncthreads();
    if (t == 0) {
      u32 tt = s_T, cum = 0;
      int d = 255;
      for (; d > 0; d--) {
        const u32 cc = hist[d];
        if (cum + cc >= tt) break;
        cum += cc;
      }
      s_prefix = (s_prefix << 8) | (u64)(u32)d;
      s_T = tt - cum;
    }
    __syncthreads();
  }
  const u64 pivot = s_prefix;
  for (int i = t; i < 8192; i += 1024) skeys[i] = 0ull;
  __syncthreads();
  for (int i = t; i < NANCH; i += 1024) {
    const u64 k = kb[i];
    if (k >= pivot) {
      const u32 p = atomicAdd(&s_cnt, 1u);
      if (p < 8192u) skeys[p] = k;
    }
  }
  __syncthreads();
  for (int kk = 2; kk <= 8192; kk <<= 1) {
    for (int j = kk >> 1; j > 0; j >>= 1) {
      for (int i = t; i < 8192; i += 1024) {
        const int ixj = i ^ j;
        if (ixj > i) {
          const u64 va = skeys[i], vb = skeys[ixj];
          const bool sw = ((i & kk) == 0) ? (va < vb) : (va > vb);
          if (sw) { skeys[i] = vb; skeys[ixj] = va; }
        }
      }
      __syncthreads();
    }
  }
  const float* bx = boxes + (size_t)b * NANCH * 4;
  float* ob = sortedBoxes + (size_t)b * PRE_NMS * 4;
  for (int i = t; i < PRE_NMS; i += 1024) {
    u32 idx = 0xFFFFFFFFu - (u32)(skeys[i] & 0xFFFFFFFFull);
    if (idx >= NANCH) idx = 0;
    const float4 v = *(const float4*)(bx + (size_t)idx * 4);
    *(float4*)(ob + (size_t)i * 4) = v;
  }
}

// ---- fast NMS: first-valid-in-sorted-order == reference argmax semantics ----
__global__ __launch_bounds__(1024) void nms_fast(const float* __restrict__ sortedBoxes,
                                                 float* __restrict__ rois) {
  const int b = blockIdx.x;
  const int t = threadIdx.x;
  __shared__ u64 valid[NMS_WORDS];
  __shared__ int keep[POST_NMS];
  __shared__ float pbox[4];
  __shared__ int s_hint;
  const float* sb = sortedBoxes + (size_t)b * PRE_NMS * 4;
  float bx[6][4];
#pragma unroll
  for (int c = 0; c < 6; c++) {
    const int id = c * 1024 + t;
    float4 v = {-1.f, -1.f, -1.f, -1.f};
    if (id < PRE_NMS) v = *(const float4*)(sb + (size_t)id * 4);
    bx[c][0] = v.x; bx[c][1] = v.y; bx[c][2] = v.z; bx[c][3] = v.w;
  }
  if (t < NMS_WORDS) valid[t] = (t == NMS_WORDS - 1) ? ((1ull << 48) - 1ull) : ~0ull;
  if (t == 0) s_hint = 0;
  __syncthreads();
  for (int p = 0; p < POST_NMS; p++) {
    if (t == 0) {
      int wdi = s_hint;
      while (wdi < NMS_WORDS && valid[wdi] == 0ull) wdi++;
      int pick;
      if (wdi < NMS_WORDS) {
        pick = wdi * 64 + (__ffsll(valid[wdi]) - 1);
        s_hint = wdi;
      } else {
        pick = 0;
      }
      keep[p] = pick;
      const float* pp = sb + (size_t)pick * 4;
      pbox[0] = pp[0]; pbox[1] = pp[1]; pbox[2] = pp[2]; pbox[3] = pp[3];
    }
    __syncthreads();
    const float px1 = pbox[0], py1 = pbox[1], px2 = pbox[2], py2 = pbox[3];
    const float parea = (px2 - px1 + 1.f) * (py2 - py1 + 1.f);
#pragma unroll
    for (int c = 0; c < 6; c++) {
      const int id = c * 1024 + t;
      const float xx1 = fmaxf(px1, bx[c][0]);
      const float yy1 = fmaxf(py1, bx[c][1]);
      const float xx2 = fminf(px2, bx[c][2]);
      const float yy2 = fminf(py2, bx[c][3]);
      const float inter = fmaxf(0.f, xx2 - xx1 + 1.f) * fmaxf(0.f, yy2 - yy1 + 1.f);
      const float a2 = (bx[c][2] - bx[c][0] + 1.f) * (bx[c][3] - bx[c][1] + 1.f);
      float iou = inter / (parea + a2 - inter);
      if (id >= PRE_NMS) iou = 0.f;
      const u64 kmask = __ballot(iou > 0.7f);
      const int wdi = c * 16 + (t >> 6);
      if ((t & 63) == 0 && kmask && wdi < NMS_WORDS) valid[wdi] &= ~kmask;
    }
    __syncthreads();
  }
  float* rb = rois + (size_t)b * POST_NMS * 5;
  for (int p = t; p < POST_NMS; p += 1024) {
    const int pick = keep[p];
    rb[p * 5 + 0] = (float)b;
    rb[p * 5 + 1] = sb[pick * 4 + 0];
    rb[p * 5 + 2] = sb[pick * 4 + 1];
    rb[p * 5 + 3] = sb[pick * 4 + 2];
    rb[p * 5 + 4] = sb[pick * 4 + 3];
  }
}

extern "C" void kernel_launch(void* const* d_in, const int* in_sizes, int n_in,
                              void* d_out, int out_size, void* d_ws, size_t ws_size,
                              hipStream_t stream) {
  const float* base = (const float*)d_in[0];
  const float* im_info = (const float*)d_in[1];
  const float* conv_w = (const float*)d_in[4];
  const float* conv_b = (const float*)d_in[5];
  const float* cls_w = (const float*)d_in[6];
  const float* cls_b = (const float*)d_in[7];
  const float* bbox_w = (const float*)d_in[8];
  const float* bbox_b = (const float*)d_in[9];

  float* out = (float*)d_out;
  float* rois = out;                                   // 8*300*5
  float* prob = out + (size_t)NB * POST_NMS * 5;       // 8*18*4096
  float* bbox = prob + (size_t)NB * 18 * HW;           // 8*36*4096

  char* ws = (char*)d_ws;
  size_t off = 0;
  float* boxes = (float*)(ws + off);       off += (size_t)NB * NANCH * 4 * 4;   // 4.72 MB
  u64* keys = (u64*)(ws + off);            off += (size_t)NB * NANCH * 8;       // 2.36 MB
  float* sortedBoxes = (float*)(ws + off); off += (size_t)NB * PRE_NMS * 4 * 4; // 0.77 MB
  double* acc54 = (double*)(ws + off);     off += (size_t)NB * HW * 54 * 8;     // 14.16 MB
  float* W2f = (float*)(ws + off);         off += (size_t)CIN * CMID * 9 * 4;   // 9.44 MB
  const size_t fixed = off;
  const size_t midFullBytes = (size_t)NB * CMID * HW * 4;
  const bool bigWS = (ws_size >= fixed + midFullBytes);
  const int CHsel = bigWS ? CMID : (CMID / 2);
  float* midChunk = (float*)(ws + off);

  transpose_w3<<<dim3((CIN * CMID * 9 + 255) / 256), 256, 0, stream>>>(conv_w, W2f);
  const int nchunks = CMID / CHsel;
  for (int chunk = 0; chunk < nchunks; ++chunk) {
    conv3x3_mix<<<dim3(CHsel / 64, 32, NB), 256, 0, stream>>>(base, W2f, conv_b, midChunk,
                                                              chunk * CHsel, CHsel);
    conv1x1_f64<<<dim3(16, NB), 256, 0, stream>>>(midChunk, cls_w, bbox_w, acc54,
                                                  chunk * CHsel, CHsel, chunk == 0 ? 1 : 0);
  }
  decode_f64<<<dim3(16, NB), 256, 0, stream>>>(acc54, cls_b, bbox_b, im_info, prob, bbox, boxes, keys);
  topk_sort<<<dim3(NB), 1024, 0, stream>>>(keys, boxes, sortedBoxes);
  nms_fast<<<dim3(NB), 1024, 0, stream>>>(sortedBoxes, rois);
}

// Round 27
// 3085.990 us; speedup vs baseline: 1.5306x; 1.5306x over previous
//
#include <hip/hip_runtime.h>
#include <cstdint>

#define NB 8
#define CIN 512
#define CMID 512
#define HW 4096            // 64*64
#define NA 9
#define NANCH 36864        // HW*NA
#define PRE_NMS 6000
#define POST_NMS 300
#define NMS_WORDS 94       // ceil(6000/64)

typedef unsigned long long u64;
typedef unsigned int u32;

__device__ __forceinline__ u32 fkey(float s) {
  u32 u = __float_as_uint(s);
  return (u & 0x80000000u) ? ~u : (u | 0x80000000u);
}

// W2f[((ci*9)+k)*512 + co] = conv_w[(co*512+ci)*9 + k]  (f32, coalescing transpose)
__global__ __launch_bounds__(256) void transpose_w3(const float* __restrict__ W, float* __restrict__ W2f) {
  int id = blockIdx.x * 256 + threadIdx.x;
  if (id >= CIN * CMID * 9) return;
  int co = id & 511;
  int rem = id >> 9;
  int k = rem % 9;
  int ci = rem / 9;
  W2f[id] = W[((size_t)co * CIN + ci) * 9 + k];
}

// ---- LDS-tiled conv3x3: f32 FMAs, f64 master accumulator flushed per 4-ci step ----
// (round-24 proven config: 3.09 ms total, absmax 0.00195)
// 256-thread block = 64 cout x 2 rows x 64 px; thread: 4co x 2row x 4px.
// Error model: 36-term f32 chunks + f64 chunk-sum -> mid error ~4e-8, at/below the
// np reference's own blocked-f32 error (~5e-8). sacc dies before each barrier -> no spill.
__global__ __launch_bounds__(256, 4) void conv3x3_mix(const float* __restrict__ X, const float* __restrict__ W2f,
                                                      const float* __restrict__ bias, float* __restrict__ midC,
                                                      int co_base, int chM) {
  const int co0 = co_base + blockIdx.x * 64;
  const int y0 = blockIdx.y * 2;
  const int b = blockIdx.z;
  __shared__ float sXf[4 * 4 * 66];   // flat [ci][rr][xx]  (4.2 KB)
  __shared__ float sWf[4 * 9 * 64];   // flat [ci][k][co]   (9.2 KB)
  const int t = threadIdx.x;
  const int tc = t >> 4, tx = t & 15;

  // ---- precomputed staging descriptors (loop-invariant) ----
  int xoff[5];   // -1: no slot; -2: zero-fill (OOB halo); >=0: X offset (const part)
#pragma unroll
  for (int s = 0; s < 5; s++) {
    const int i = t + 256 * s;
    int off = -1;
    if (i < 4 * 4 * 66) {
      const int xx = i % 66;
      const int rr = (i / 66) & 3;
      const int ci = i / 264;
      const int gy = y0 - 1 + rr, gx = xx - 1;
      off = ((unsigned)gy < 64u && (unsigned)gx < 64u) ? (ci * HW + gy * 64 + gx) : -2;
    }
    xoff[s] = off;
  }
  int woff[9];
#pragma unroll
  for (int s = 0; s < 9; s++) {
    const int i = t + 256 * s;
    const int co = i & 63;
    const int r2 = i >> 6;
    woff[s] = r2 * CMID + co0 + co;
  }

  double acc[4][2][4];
#pragma unroll
  for (int j = 0; j < 4; j++)
#pragma unroll
    for (int r = 0; r < 2; r++)
#pragma unroll
      for (int q = 0; q < 4; q++) acc[j][r][q] = 0.0;

  const float* Xb = X + (size_t)b * CIN * HW;
  for (int c0 = 0; c0 < CIN; c0 += 4) {
    const float* Xc = Xb + (size_t)c0 * HW;
    const float* Wc = W2f + (size_t)c0 * 9 * CMID;
#pragma unroll
    for (int s = 0; s < 5; s++) {
      const int off = xoff[s];
      if (off != -1) {
        float v = 0.f;
        if (off >= 0) v = Xc[off];
        sXf[t + 256 * s] = v;
      }
    }
#pragma unroll
    for (int s = 0; s < 9; s++) {
      sWf[t + 256 * s] = Wc[woff[s]];
    }
    __syncthreads();

    float sacc[4][2][4];   // f32 chunk accumulator (36 terms)
#pragma unroll
    for (int j = 0; j < 4; j++)
#pragma unroll
      for (int r = 0; r < 2; r++)
#pragma unroll
        for (int q = 0; q < 4; q++) sacc[j][r][q] = 0.f;

#pragma unroll
    for (int ci = 0; ci < 4; ci++) {
#pragma unroll
      for (int ky = 0; ky < 3; ky++) {
        float xv0[6], xv1[6];
#pragma unroll
        for (int q = 0; q < 6; q++) xv0[q] = sXf[ci * 264 + ky * 66 + tx * 4 + q];        // out row 0
#pragma unroll
        for (int q = 0; q < 6; q++) xv1[q] = sXf[ci * 264 + (ky + 1) * 66 + tx * 4 + q];  // out row 1
#pragma unroll
        for (int kx = 0; kx < 3; kx++) {
          const float* wp = &sWf[ci * 576 + (ky * 3 + kx) * 64 + tc * 4];
          const float w0 = wp[0], w1 = wp[1], w2 = wp[2], w3 = wp[3];
#pragma unroll
          for (int q = 0; q < 4; q++) {
            const float a0 = xv0[q + kx];
            const float a1 = xv1[q + kx];
            sacc[0][0][q] = fmaf(w0, a0, sacc[0][0][q]);
            sacc[1][0][q] = fmaf(w1, a0, sacc[1][0][q]);
            sacc[2][0][q] = fmaf(w2, a0, sacc[2][0][q]);
            sacc[3][0][q] = fmaf(w3, a0, sacc[3][0][q]);
            sacc[0][1][q] = fmaf(w0, a1, sacc[0][1][q]);
            sacc[1][1][q] = fmaf(w1, a1, sacc[1][1][q]);
            sacc[2][1][q] = fmaf(w2, a1, sacc[2][1][q]);
            sacc[3][1][q] = fmaf(w3, a1, sacc[3][1][q]);
          }
        }
      }
    }
#pragma unroll
    for (int j = 0; j < 4; j++)
#pragma unroll
      for (int r = 0; r < 2; r++)
#pragma unroll
        for (int q = 0; q < 4; q++) acc[j][r][q] += (double)sacc[j][r][q];
    __syncthreads();
  }
#pragma unroll
  for (int j = 0; j < 4; j++) {
    const int co = co0 + tc * 4 + j;
    const double bv = (double)bias[co];
#pragma unroll
    for (int r = 0; r < 2; r++) {
      float4 o4;
      o4.x = (float)fmax(acc[j][r][0] + bv, 0.0);
      o4.y = (float)fmax(acc[j][r][1] + bv, 0.0);
      o4.z = (float)fmax(acc[j][r][2] + bv, 0.0);
      o4.w = (float)fmax(acc[j][r][3] + bv, 0.0);
      *(float4*)&midC[((size_t)b * chM + (co - co_base)) * HW + (y0 + r) * 64 + tx * 4] = o4;
    }
  }
}

// ---- merged 1x1 (cls 18 + bbox 36), FP64 accumulate over chM channels ----
__global__ __launch_bounds__(256) void conv1x1_f64(const float* __restrict__ midC, const float* __restrict__ clsW,
                                                   const float* __restrict__ bboxW, double* __restrict__ acc54,
                                                   int co_base, int chM, int first) {
  const int b = blockIdx.y;
  const int pix = blockIdx.x * 256 + threadIdx.x;
  const float* mb = midC + (size_t)b * chM * HW + pix;
  double a[54];
#pragma unroll
  for (int o = 0; o < 54; o++) a[o] = 0.0;
  for (int c = 0; c < chM; c++) {
    const double xv = (double)mb[(size_t)c * HW];
    const int ci = co_base + c;
#pragma unroll
    for (int o = 0; o < 18; o++) a[o] = fma(xv, (double)clsW[(size_t)o * CIN + ci], a[o]);
#pragma unroll
    for (int o = 0; o < 36; o++) a[18 + o] = fma(xv, (double)bboxW[(size_t)o * CIN + ci], a[18 + o]);
  }
  double* ap = acc54 + ((size_t)b * HW + pix) * 54;
  if (first) {
#pragma unroll
    for (int o = 0; o < 54; o++) ap[o] = a[o];
  } else {
#pragma unroll
    for (int o = 0; o < 54; o++) ap[o] += a[o];
  }
}

// ---- softmax + anchor decode + key build, FP64 math, f32 at np-visible points ----
__global__ __launch_bounds__(256) void decode_f64(const double* __restrict__ acc54,
                                                  const float* __restrict__ clsB, const float* __restrict__ bboxB,
                                                  const float* __restrict__ im_info,
                                                  float* __restrict__ probOut, float* __restrict__ bboxOut,
                                                  float* __restrict__ boxes, u64* __restrict__ keys) {
  const int b = blockIdx.y;
  const int pix = blockIdx.x * 256 + threadIdx.x;
  const double* ap = acc54 + ((size_t)b * HW + pix) * 54;
  double c[18];
#pragma unroll
  for (int o = 0; o < 18; o++) c[o] = ap[o] + (double)clsB[o];

  const int h = pix >> 6, w = pix & 63;
  float* pb = probOut + (size_t)b * 18 * HW + pix;
  float* bb = bboxOut + (size_t)b * 36 * HW + pix;
#pragma unroll
  for (int o = 0; o < 36; o++) bb[(size_t)o * HW] = (float)(ap[18 + o] + (double)bboxB[o]);

  const float imWm1 = im_info[b * 3 + 1] - 1.0f;
  const float imHm1 = im_info[b * 3 + 0] - 1.0f;
  const float msf = 16.0f * im_info[b * 3 + 2];
  float4* bxout = (float4*)(boxes + ((size_t)b * NANCH + (size_t)pix * NA) * 4);
  u64* kout = keys + (size_t)b * NANCH + (size_t)pix * NA;
  const float ratios[3] = {0.5f, 1.0f, 2.0f};
  const float scales[3] = {8.0f, 16.0f, 32.0f};
#pragma unroll
  for (int a = 0; a < NA; a++) {
    const double c0v = c[a], c1v = c[9 + a];
    const double m = fmax(c0v, c1v);
    const double e0 = exp(c0v - m), e1 = exp(c1v - m);
    const double s = e0 + e1;
    pb[(size_t)a * HW] = (float)(e0 / s);
    const double p1 = e1 / s;
    pb[(size_t)(9 + a) * HW] = (float)p1;

    const double dx = ap[18 + 4 * a + 0] + (double)bboxB[4 * a + 0];
    const double dy = ap[18 + 4 * a + 1] + (double)bboxB[4 * a + 1];
    const double dw = ap[18 + 4 * a + 2] + (double)bboxB[4 * a + 2];
    const double dh = ap[18 + 4 * a + 3] + (double)bboxB[4 * a + 3];

    const float sq = sqrtf(ratios[a / 3]);
    const float wa = (16.0f / sq) * scales[a % 3];
    const float ha = (16.0f * sq) * scales[a % 3];
    const float ax1 = (7.5f - 0.5f * (wa - 1.0f)) + (float)(w * 16);
    const float ay1 = (7.5f - 0.5f * (ha - 1.0f)) + (float)(h * 16);
    const float ax2 = (7.5f + 0.5f * (wa - 1.0f)) + (float)(w * 16);
    const float ay2 = (7.5f + 0.5f * (ha - 1.0f)) + (float)(h * 16);
    const float awf = ax2 - ax1 + 1.0f;
    const float ahf = ay2 - ay1 + 1.0f;
    const float cxf = ax1 + 0.5f * awf;
    const float cyf = ay1 + 0.5f * ahf;

    const double pcx = dx * (double)awf + (double)cxf;
    const double pcy = dy * (double)ahf + (double)cyf;
    const double pw = exp(dw) * (double)awf;
    const double ph = exp(dh) * (double)ahf;
    double x1 = pcx - 0.5 * pw;
    double y1 = pcy - 0.5 * ph;
    double x2 = pcx + 0.5 * pw;
    double y2 = pcy + 0.5 * ph;
    x1 = fmin(fmax(x1, 0.0), (double)imWm1);
    y1 = fmin(fmax(y1, 0.0), (double)imHm1);
    x2 = fmin(fmax(x2, 0.0), (double)imWm1);
    y2 = fmin(fmax(y2, 0.0), (double)imHm1);
    const float x1f = (float)x1, y1f = (float)y1, x2f = (float)x2, y2f = (float)y2;
    const bool ok = (x2f - x1f + 1.0f >= msf) && (y2f - y1f + 1.0f >= msf);
    const float sc = ok ? (float)p1 : -1000000000.0f;
    float4 bo;
    bo.x = x1f; bo.y = y1f; bo.z = x2f; bo.w = y2f;
    bxout[a] = bo;
    const u32 n = (u32)(pix * NA + a);
    kout[a] = ((u64)fkey(sc) << 32) | (u64)(0xFFFFFFFFu - n);
  }
}

// ---- exact top-6000: radix select on unique keys + bitonic sort + gather ----
__global__ __launch_bounds__(1024) void topk_sort(const u64* __restrict__ keys, const float* __restrict__ boxes,
                                                  float* __restrict__ sortedBoxes) {
  const int b = blockIdx.x;
  const int t = threadIdx.x;
  __shared__ u64 skeys[8192];   // 64 KiB static
  __shared__ u32 hist[256];
  __shared__ u64 s_prefix;
  __shared__ u32 s_T, s_cnt;
  const u64* kb = keys + (size_t)b * NANCH;
  if (t == 0) { s_prefix = 0ull; s_T = PRE_NMS; s_cnt = 0u; }
  __syncthreads();
  for (int pass = 0; pass < 8; pass++) {
    const int shift = 56 - 8 * pass;
    if (t < 256) hist[t] = 0u;
    __syncthreads();
    const u64 pfx = s_prefix;
    for (int i = t; i < NANCH; i += 1024) {
      const u64 k = kb[i];
      if (pass == 0 || (k >> (shift + 8)) == pfx)
        atomicAdd(&hist[(u32)((k >> shift) & 255ull)], 1u);
    }
    __syncthreads();
    if (t == 0) {
      u32 tt = s_T, cum = 0;
      int d = 255;
      for (; d > 0; d--) {
        const u32 cc = hist[d];
        if (cum + cc >= tt) break;
        cum += cc;
      }
      s_prefix = (s_prefix << 8) | (u64)(u32)d;
      s_T = tt - cum;
    }
    __syncthreads();
  }
  const u64 pivot = s_prefix;
  for (int i = t; i < 8192; i += 1024) skeys[i] = 0ull;
  __syncthreads();
  for (int i = t; i < NANCH; i += 1024) {
    const u64 k = kb[i];
    if (k >= pivot) {
      const u32 p = atomicAdd(&s_cnt, 1u);
      if (p < 8192u) skeys[p] = k;
    }
  }
  __syncthreads();
  for (int kk = 2; kk <= 8192; kk <<= 1) {
    for (int j = kk >> 1; j > 0; j >>= 1) {
      for (int i = t; i < 8192; i += 1024) {
        const int ixj = i ^ j;
        if (ixj > i) {
          const u64 va = skeys[i], vb = skeys[ixj];
          const bool sw = ((i & kk) == 0) ? (va < vb) : (va > vb);
          if (sw) { skeys[i] = vb; skeys[ixj] = va; }
        }
      }
      __syncthreads();
    }
  }
  const float* bx = boxes + (size_t)b * NANCH * 4;
  float* ob = sortedBoxes + (size_t)b * PRE_NMS * 4;
  for (int i = t; i < PRE_NMS; i += 1024) {
    u32 idx = 0xFFFFFFFFu - (u32)(skeys[i] & 0xFFFFFFFFull);
    if (idx >= NANCH) idx = 0;
    const float4 v = *(const float4*)(bx + (size_t)idx * 4);
    *(float4*)(ob + (size_t)i * 4) = v;
  }
}

// ---- fast NMS: first-valid-in-sorted-order == reference argmax semantics ----
__global__ __launch_bounds__(1024) void nms_fast(const float* __restrict__ sortedBoxes,
                                                 float* __restrict__ rois) {
  const int b = blockIdx.x;
  const int t = threadIdx.x;
  __shared__ u64 valid[NMS_WORDS];
  __shared__ int keep[POST_NMS];
  __shared__ float pbox[4];
  __shared__ int s_hint;
  const float* sb = sortedBoxes + (size_t)b * PRE_NMS * 4;
  float bx[6][4];
#pragma unroll
  for (int c = 0; c < 6; c++) {
    const int id = c * 1024 + t;
    float4 v = {-1.f, -1.f, -1.f, -1.f};
    if (id < PRE_NMS) v = *(const float4*)(sb + (size_t)id * 4);
    bx[c][0] = v.x; bx[c][1] = v.y; bx[c][2] = v.z; bx[c][3] = v.w;
  }
  if (t < NMS_WORDS) valid[t] = (t == NMS_WORDS - 1) ? ((1ull << 48) - 1ull) : ~0ull;
  if (t == 0) s_hint = 0;
  __syncthreads();
  for (int p = 0; p < POST_NMS; p++) {
    if (t == 0) {
      int wdi = s_hint;
      while (wdi < NMS_WORDS && valid[wdi] == 0ull) wdi++;
      int pick;
      if (wdi < NMS_WORDS) {
        pick = wdi * 64 + (__ffsll(valid[wdi]) - 1);
        s_hint = wdi;
      } else {
        pick = 0;
      }
      keep[p] = pick;
      const float* pp = sb + (size_t)pick * 4;
      pbox[0] = pp[0]; pbox[1] = pp[1]; pbox[2] = pp[2]; pbox[3] = pp[3];
    }
    __syncthreads();
    const float px1 = pbox[0], py1 = pbox[1], px2 = pbox[2], py2 = pbox[3];
    const float parea = (px2 - px1 + 1.f) * (py2 - py1 + 1.f);
#pragma unroll
    for (int c = 0; c < 6; c++) {
      const int id = c * 1024 + t;
      const float xx1 = fmaxf(px1, bx[c][0]);
      const float yy1 = fmaxf(py1, bx[c][1]);
      const float xx2 = fminf(px2, bx[c][2]);
      const float yy2 = fminf(py2, bx[c][3]);
      const float inter = fmaxf(0.f, xx2 - xx1 + 1.f) * fmaxf(0.f, yy2 - yy1 + 1.f);
      const float a2 = (bx[c][2] - bx[c][0] + 1.f) * (bx[c][3] - bx[c][1] + 1.f);
      float iou = inter / (parea + a2 - inter);
      if (id >= PRE_NMS) iou = 0.f;
      const u64 kmask = __ballot(iou > 0.7f);
      const int wdi = c * 16 + (t >> 6);
      if ((t & 63) == 0 && kmask && wdi < NMS_WORDS) valid[wdi] &= ~kmask;
    }
    __syncthreads();
  }
  float* rb = rois + (size_t)b * POST_NMS * 5;
  for (int p = t; p < POST_NMS; p += 1024) {
    const int pick = keep[p];
    rb[p * 5 + 0] = (float)b;
    rb[p * 5 + 1] = sb[pick * 4 + 0];
    rb[p * 5 + 2] = sb[pick * 4 + 1];
    rb[p * 5 + 3] = sb[pick * 4 + 2];
    rb[p * 5 + 4] = sb[pick * 4 + 3];
  }
}

extern "C" void kernel_launch(void* const* d_in, const int* in_sizes, int n_in,
                              void* d_out, int out_size, void* d_ws, size_t ws_size,
                              hipStream_t stream) {
  const float* base = (const float*)d_in[0];
  const float* im_info = (const float*)d_in[1];
  const float* conv_w = (const float*)d_in[4];
  const float* conv_b = (const float*)d_in[5];
  const float* cls_w = (const float*)d_in[6];
  const float* cls_b = (const float*)d_in[7];
  const float* bbox_w = (const float*)d_in[8];
  const float* bbox_b = (const float*)d_in[9];

  float* out = (float*)d_out;
  float* rois = out;                                   // 8*300*5
  float* prob = out + (size_t)NB * POST_NMS * 5;       // 8*18*4096
  float* bbox = prob + (size_t)NB * 18 * HW;           // 8*36*4096

  char* ws = (char*)d_ws;
  size_t off = 0;
  float* boxes = (float*)(ws + off);       off += (size_t)NB * NANCH * 4 * 4;   // 4.72 MB
  u64* keys = (u64*)(ws + off);            off += (size_t)NB * NANCH * 8;       // 2.36 MB
  float* sortedBoxes = (float*)(ws + off); off += (size_t)NB * PRE_NMS * 4 * 4; // 0.77 MB
  double* acc54 = (double*)(ws + off);     off += (size_t)NB * HW * 54 * 8;     // 14.16 MB
  float* W2f = (float*)(ws + off);         off += (size_t)CIN * CMID * 9 * 4;   // 9.44 MB
  const size_t fixed = off;
  const size_t midFullBytes = (size_t)NB * CMID * HW * 4;
  const bool bigWS = (ws_size >= fixed + midFullBytes);
  const int CHsel = bigWS ? CMID : (CMID / 2);
  float* midChunk = (float*)(ws + off);

  transpose_w3<<<dim3((CIN * CMID * 9 + 255) / 256), 256, 0, stream>>>(conv_w, W2f);
  const int nchunks = CMID / CHsel;
  for (int chunk = 0; chunk < nchunks; ++chunk) {
    conv3x3_mix<<<dim3(CHsel / 64, 32, NB), 256, 0, stream>>>(base, W2f, conv_b, midChunk,
                                                              chunk * CHsel, CHsel);
    conv1x1_f64<<<dim3(16, NB), 256, 0, stream>>>(midChunk, cls_w, bbox_w, acc54,
                                                  chunk * CHsel, CHsel, chunk == 0 ? 1 : 0);
  }
  decode_f64<<<dim3(16, NB), 256, 0, stream>>>(acc54, cls_b, bbox_b, im_info, prob, bbox, boxes, keys);
  topk_sort<<<dim3(NB), 1024, 0, stream>>>(keys, boxes, sortedBoxes);
  nms_fast<<<dim3(NB), 1024, 0, stream>>>(sortedBoxes, rois);
}